// Round 4
// baseline (132.810 us; speedup 1.0000x reference)
//
#include <hip/hip_runtime.h>

using f32x4 = __attribute__((ext_vector_type(4))) float;
using s16x8 = __attribute__((ext_vector_type(8))) short;

static __device__ __forceinline__ unsigned short f2bf(float f){
  union { float f; unsigned int i; } c; c.f = f;
  return (unsigned short)((c.i + 0x7FFFu + ((c.i >> 16) & 1u)) >> 16);
}
static __device__ __forceinline__ s16x8 ld8(const unsigned short* p){
  return *(const s16x8*)p;
}
static __device__ __forceinline__ s16x8 cvt8(const float* p){
  const float4* q = (const float4*)p;
  float4 a = q[0], b = q[1];
  s16x8 r;
  r[0]=(short)f2bf(a.x); r[1]=(short)f2bf(a.y); r[2]=(short)f2bf(a.z); r[3]=(short)f2bf(a.w);
  r[4]=(short)f2bf(b.x); r[5]=(short)f2bf(b.y); r[6]=(short)f2bf(b.z); r[7]=(short)f2bf(b.w);
  return r;
}
static __device__ __forceinline__ f32x4 mfma16(s16x8 a, s16x8 b, f32x4 c){
  return __builtin_amdgcn_mfma_f32_16x16x32_bf16(a, b, c, 0, 0, 0);
}

// ============ kernel A: proj (waves 0-1) + distributed FFN-weight prep (waves 2-3) ============
// grid 256 x 256thr. Waves 0-1: LDS-stage Wp/Wqkv then compute 32 rows of q/k/vt.
// Waves 2-3: write this block's 1/256 slice of wf1t/wf2t/ws1t/cbp (global, disjoint);
// block 1 also computes rel_t. Prep hides under proj staging/compute; saves a kernel launch.
__global__ __launch_bounds__(256) void k_proj(const float* __restrict__ x,
    const float* __restrict__ Wp, const float* __restrict__ bp,
    const float* __restrict__ Wq, const float* __restrict__ bq,
    const float* __restrict__ Wk, const float* __restrict__ bk,
    const float* __restrict__ Wv, const float* __restrict__ bv,
    const float* __restrict__ Ee, const float* __restrict__ Wr1,
    const float* __restrict__ br1, const float* __restrict__ Wr2,
    const float* __restrict__ Wf1, const float* __restrict__ bf1,
    const float* __restrict__ Wf2, const float* __restrict__ bf2,
    const float* __restrict__ lng, const float* __restrict__ lnb,
    const float* __restrict__ Ws1, const float* __restrict__ bs1,
    const float* __restrict__ Ws2, const float* __restrict__ bs2,
    unsigned short* __restrict__ q, unsigned short* __restrict__ kk,
    unsigned short* __restrict__ vt,
    unsigned short* __restrict__ wf1t, unsigned short* __restrict__ wf2t,
    unsigned short* __restrict__ ws1t, float* __restrict__ cbp,
    float* __restrict__ rel_t)
{
  __shared__ __align__(16) unsigned short WpT[64*264];   // Wp^T [n][k]
  __shared__ __align__(16) unsigned short Wt3[3][64*72]; // Wq/Wk/Wv^T [n][k]
  __shared__ __align__(16) unsigned short xs[2][16*72];  // per-wave xp tile

  int t = threadIdx.x, bid = blockIdx.x;
  int row0b = bid*32;

  // L2-warm touch of this block's 32 x-rows (256 x 128B lines) during staging
  float tc = x[row0b*256 + t*32];

  // stage Wp^T / Wqkv^T via float4, all 256 threads
  const float4* Wp4 = (const float4*)Wp;
  for (int i = t; i < 4096; i += 256){
    float4 v = Wp4[i];
    int k = i >> 4, n = (i & 15) * 4;
    WpT[(n+0)*264+k] = f2bf(v.x);
    WpT[(n+1)*264+k] = f2bf(v.y);
    WpT[(n+2)*264+k] = f2bf(v.z);
    WpT[(n+3)*264+k] = f2bf(v.w);
  }
  const float4* Wq4 = (const float4*)Wq;
  const float4* Wk4 = (const float4*)Wk;
  const float4* Wv4 = (const float4*)Wv;
  for (int i = t; i < 1024; i += 256){
    int k = i >> 4, n = (i & 15) * 4;
    float4 a = Wq4[i], b2 = Wk4[i], c2 = Wv4[i];
    Wt3[0][(n+0)*72+k]=f2bf(a.x);  Wt3[0][(n+1)*72+k]=f2bf(a.y);
    Wt3[0][(n+2)*72+k]=f2bf(a.z);  Wt3[0][(n+3)*72+k]=f2bf(a.w);
    Wt3[1][(n+0)*72+k]=f2bf(b2.x); Wt3[1][(n+1)*72+k]=f2bf(b2.y);
    Wt3[1][(n+2)*72+k]=f2bf(b2.z); Wt3[1][(n+3)*72+k]=f2bf(b2.w);
    Wt3[2][(n+0)*72+k]=f2bf(c2.x); Wt3[2][(n+1)*72+k]=f2bf(c2.y);
    Wt3[2][(n+2)*72+k]=f2bf(c2.z); Wt3[2][(n+3)*72+k]=f2bf(c2.w);
  }

  // waves 2-3: this block's prep slice (disjoint across blocks; coalesced f32 reads)
  if (t >= 128){
    int u = t - 128;
    if (u < 32){                       // Wf1 (64x128) -> wf1t [j][d] stride 64
      int e = bid*32 + u;
      wf1t[(e&127)*64 + (e>>7)] = f2bf(Wf1[e]);
    } else if (u < 64){                // Wf2 (128x64) -> wf2t [n][k] stride 128
      int e = bid*32 + (u-32);
      wf2t[(e&63)*128 + (e>>6)] = f2bf(Wf2[e]);
    } else if (u < 72){                // Ws1 (64x32) -> ws1t [c][d] stride 64
      int e = bid*8 + (u-64);
      ws1t[(e&31)*64 + (e>>5)] = f2bf(Ws1[e]);
    } else if (u < 76){                // cbp pack: 385 f32 (blocks 0..96)
      int idx = bid*4 + (u-72);
      if (idx < 385){
        float v;
        if      (idx < 128) v = bf1[idx];
        else if (idx < 192) v = bf2[idx-128];
        else if (idx < 256) v = lng[idx-192];
        else if (idx < 320) v = lnb[idx-256];
        else if (idx < 352) v = bs1[idx-320];
        else if (idx < 384) v = Ws2[idx-352];
        else                v = bs2[0];
        cbp[idx] = v;
      }
    } else if (bid == 1 && u >= 76 && u < 127){   // rel table (block 1)
      int dd = u - 76;
      float e[32];
      const float4* e4 = (const float4*)(Ee + dd*32);
#pragma unroll
      for (int j = 0; j < 8; ++j){
        float4 v = e4[j];
        e[j*4+0]=v.x; e[j*4+1]=v.y; e[j*4+2]=v.z; e[j*4+3]=v.w;
      }
      float w = 0.f;
      for (int h = 0; h < 16; ++h){
        float s = br1[h];
#pragma unroll
        for (int j = 0; j < 32; ++j) s += e[j] * Wr1[j*16 + h];
        w += fmaxf(s, 0.f) * Wr2[h];
      }
      rel_t[dd] = 1.f / (1.f + __expf(-w));
    }
  }
  asm volatile("" :: "v"(tc));   // keep x touch alive
  __syncthreads();

  if (t < 128){
    int lane = t & 63, wave = t >> 6, colL = lane & 15, quad = lane >> 4;
    int row0 = row0b + wave*16;

    const float* xr = x + (row0 + colL)*256;    // L2-warm after touch
    f32x4 acc[4] = {};
#pragma unroll
    for (int kc = 0; kc < 256; kc += 32){
      s16x8 a = cvt8(xr + kc + quad*8);
#pragma unroll
      for (int nt = 0; nt < 4; ++nt)
        acc[nt] = mfma16(a, ld8(&WpT[(nt*16+colL)*264 + kc + quad*8]), acc[nt]);
    }
    unsigned short* xw = xs[wave];
#pragma unroll
    for (int nt = 0; nt < 4; ++nt){
      int col = nt*16 + colL;
      float bb = bp[col];
#pragma unroll
      for (int i = 0; i < 4; ++i)
        xw[(quad*4+i)*72 + col] = f2bf(acc[nt][i] + bb);
    }
    // own-wave LDS write->read: compiler inserts lgkmcnt wait; no barrier needed
    s16x8 a0 = ld8(&xw[colL*72 +  0 + quad*8]);
    s16x8 a1 = ld8(&xw[colL*72 + 32 + quad*8]);

#pragma unroll
    for (int w = 0; w < 3; ++w){
      const float* bias = w==0 ? bq : (w==1 ? bk : bv);
      f32x4 c[4] = {};
#pragma unroll
      for (int nt = 0; nt < 4; ++nt){
        c[nt] = mfma16(a0, ld8(&Wt3[w][(nt*16+colL)*72 +  0 + quad*8]), c[nt]);
        c[nt] = mfma16(a1, ld8(&Wt3[w][(nt*16+colL)*72 + 32 + quad*8]), c[nt]);
      }
#pragma unroll
      for (int nt = 0; nt < 4; ++nt){
        int col = nt*16 + colL;
        float bb = bias[col];
#pragma unroll
        for (int i = 0; i < 4; ++i){
          int row = row0 + quad*4 + i;
          float v = c[nt][i] + bb;
          if (w == 0)      q [row*64 + col] = f2bf(v);
          else if (w == 1) kk[row*64 + col] = f2bf(v);
          else             vt[(row>>9)*32768 + col*512 + (row & 511)] = f2bf(v);
        }
      }
    }
  }
}

// ============ kernel B: staging-free attention + FFN + LN + head (unchanged, verified) ============
// grid (32 qtiles, 16 batches) x 256thr; 4-way key split; ao stays in LDS.
__global__ __launch_bounds__(256) void k_attn_ffn(const unsigned short* __restrict__ q,
    const unsigned short* __restrict__ kmat, const unsigned short* __restrict__ vt,
    const int* __restrict__ ranks, const float* __restrict__ rel_t,
    const unsigned short* __restrict__ wf1t, const unsigned short* __restrict__ wf2t,
    const unsigned short* __restrict__ ws1t, const float* __restrict__ cbp,
    float* __restrict__ out)
{
  __shared__ __align__(16) int r_s[512];
  __shared__ float rt_s[64];
  __shared__ float pmax_s[4][16], psum_s[4][16];
  __shared__ __align__(16) unsigned short Pbuf[4*16*136]; // P; later aoS(@0)+hbuf(@2176)
  __shared__ __align__(16) float Opart[4][16*66];
  __shared__ float cb[388];

  int b = blockIdx.y, qt = blockIdx.x;
  int t = threadIdx.x, lane = t & 63, wave = t >> 6;
  int colL = lane & 15, quad = lane >> 4;

  // ---- tiny staging (ranks / rel table / packed cb), overlaps QK^T ----
  if (t < 128) ((int4*)r_s)[t] = ((const int4*)(ranks + b*512))[t];
  if (t < 64) rt_s[t] = (t < 51) ? rel_t[t] : 0.f;
  if (t >= 64 && t < 161){
    int u = t - 64;
    if (u < 96) ((float4*)cb)[u] = ((const float4*)cbp)[u];
    else        cb[384] = cbp[384];
  }

  // ---- QK^T ----
  int qrow0 = qt*16;
  const unsigned short* qp = q    + b*32768;
  const unsigned short* kp = kmat + b*32768;
  const unsigned short* vp = vt   + b*32768;

  s16x8 aq0 = ld8(qp + (qrow0+colL)*64 +  0 + quad*8);
  s16x8 aq1 = ld8(qp + (qrow0+colL)*64 + 32 + quad*8);

  int key0 = wave*128;
  f32x4 S[8];
#pragma unroll
  for (int mt = 0; mt < 8; ++mt){
    int key = key0 + mt*16 + colL;
    f32x4 c = {};
    c = mfma16(aq0, ld8(kp + key*64 +  0 + quad*8), c);
    c = mfma16(aq1, ld8(kp + key*64 + 32 + quad*8), c);
    S[mt] = c;
  }
  __syncthreads();   // r_s/rt_s/cb ready

  int rq[4];
#pragma unroll
  for (int i = 0; i < 4; ++i) rq[i] = r_s[qrow0 + quad*4 + i];

  float rmax[4] = {-1e30f,-1e30f,-1e30f,-1e30f};
#pragma unroll
  for (int mt = 0; mt < 8; ++mt){
    int rm = r_s[key0 + mt*16 + colL];
#pragma unroll
    for (int i = 0; i < 4; ++i){
      int dd = rq[i] - rm; dd = dd < 0 ? -dd : dd; dd = dd > 50 ? 50 : dd;
      float s = S[mt][i] * 0.125f * rt_s[dd];
      S[mt][i] = s;
      rmax[i] = fmaxf(rmax[i], s);
    }
  }
#pragma unroll
  for (int i = 0; i < 4; ++i){
    rmax[i] = fmaxf(rmax[i], __shfl_xor(rmax[i], 1));
    rmax[i] = fmaxf(rmax[i], __shfl_xor(rmax[i], 2));
    rmax[i] = fmaxf(rmax[i], __shfl_xor(rmax[i], 4));
    rmax[i] = fmaxf(rmax[i], __shfl_xor(rmax[i], 8));
  }
  if (colL == 0){
#pragma unroll
    for (int i = 0; i < 4; ++i) pmax_s[wave][quad*4 + i] = rmax[i];
  }
  __syncthreads();
  float gmax[4];
#pragma unroll
  for (int i = 0; i < 4; ++i){
    int r = quad*4 + i;
    gmax[i] = fmaxf(fmaxf(pmax_s[0][r], pmax_s[1][r]), fmaxf(pmax_s[2][r], pmax_s[3][r]));
  }
  float rsum[4] = {0.f,0.f,0.f,0.f};
#pragma unroll
  for (int mt = 0; mt < 8; ++mt){
#pragma unroll
    for (int i = 0; i < 4; ++i){
      float p = __expf(S[mt][i] - gmax[i]);
      S[mt][i] = p;
      rsum[i] += p;
    }
  }
#pragma unroll
  for (int i = 0; i < 4; ++i){
    rsum[i] += __shfl_xor(rsum[i], 1);
    rsum[i] += __shfl_xor(rsum[i], 2);
    rsum[i] += __shfl_xor(rsum[i], 4);
    rsum[i] += __shfl_xor(rsum[i], 8);
  }
  if (colL == 0){
#pragma unroll
    for (int i = 0; i < 4; ++i) psum_s[wave][quad*4 + i] = rsum[i];
  }
  __syncthreads();
  float inv[4];
#pragma unroll
  for (int i = 0; i < 4; ++i){
    int r = quad*4 + i;
    inv[i] = 1.f / (psum_s[0][r] + psum_s[1][r] + psum_s[2][r] + psum_s[3][r]);
  }
  unsigned short* Pw = Pbuf + wave*(16*136);
#pragma unroll
  for (int mt = 0; mt < 8; ++mt){
#pragma unroll
    for (int i = 0; i < 4; ++i)
      Pw[(quad*4+i)*136 + mt*16 + colL] = f2bf(S[mt][i] * inv[i]);
  }
  // PV on own-wave P (no barrier needed)
  f32x4 O[4] = {};
#pragma unroll
  for (int mc = 0; mc < 128; mc += 32){
    s16x8 ap = ld8(&Pw[colL*136 + mc + quad*8]);
#pragma unroll
    for (int dt = 0; dt < 4; ++dt)
      O[dt] = mfma16(ap, ld8(vp + (dt*16+colL)*512 + key0 + mc + quad*8), O[dt]);
  }
  float* Ow = Opart[wave];
#pragma unroll
  for (int dt = 0; dt < 4; ++dt)
#pragma unroll
    for (int i = 0; i < 4; ++i)
      Ow[(quad*4+i)*66 + dt*16 + colL] = O[dt][i];
  __syncthreads();             // P dead from here; reuse Pbuf as aoS/hbuf
  unsigned short* aoS = Pbuf;  // 16x72
  for (int e = t; e < 1024; e += 256){
    int row = e >> 6, col = e & 63;
    float s = Opart[0][row*66+col] + Opart[1][row*66+col]
            + Opart[2][row*66+col] + Opart[3][row*66+col];
    aoS[row*72 + col] = f2bf(s);
  }
  __syncthreads();

  // ---- FFN + LayerNorm + head on this block's 16 rows (wave 0) ----
  if (wave == 0){
    unsigned short* hw = Pbuf + 2176;   // 16x136 scratch (old P[1] region)
    int row0g = b*512 + qt*16;

    f32x4 a1[8] = {};
#pragma unroll
    for (int kc = 0; kc < 64; kc += 32){
      s16x8 a = ld8(&aoS[colL*72 + kc + quad*8]);
#pragma unroll
      for (int nt = 0; nt < 8; ++nt)
        a1[nt] = mfma16(a, ld8(&wf1t[(nt*16+colL)*64 + kc + quad*8]), a1[nt]);
    }
#pragma unroll
    for (int nt = 0; nt < 8; ++nt){
      int col = nt*16 + colL;
      float bb = cb[col];
#pragma unroll
      for (int i = 0; i < 4; ++i)
        hw[(quad*4+i)*136 + col] = f2bf(fmaxf(a1[nt][i] + bb, 0.f));
    }
    f32x4 a2[4] = {};
#pragma unroll
    for (int kc = 0; kc < 128; kc += 32){
      s16x8 a = ld8(&hw[colL*136 + kc + quad*8]);
#pragma unroll
      for (int nt = 0; nt < 4; ++nt)
        a2[nt] = mfma16(a, ld8(&wf2t[(nt*16+colL)*128 + kc + quad*8]), a2[nt]);
    }
    float vals[4][4];
#pragma unroll
    for (int nt = 0; nt < 4; ++nt){
      float bb = cb[128 + nt*16 + colL];
#pragma unroll
      for (int i = 0; i < 4; ++i) vals[i][nt] = a2[nt][i] + bb;
    }
    float hnv[4][4];
#pragma unroll
    for (int i = 0; i < 4; ++i){
      float s = vals[i][0]+vals[i][1]+vals[i][2]+vals[i][3];
      s += __shfl_xor(s,1); s += __shfl_xor(s,2); s += __shfl_xor(s,4); s += __shfl_xor(s,8);
      float mu = s * (1.f/64.f);
      float d0=vals[i][0]-mu, d1=vals[i][1]-mu, d2=vals[i][2]-mu, d3=vals[i][3]-mu;
      float s2 = d0*d0 + d1*d1 + d2*d2 + d3*d3;
      s2 += __shfl_xor(s2,1); s2 += __shfl_xor(s2,2); s2 += __shfl_xor(s2,4); s2 += __shfl_xor(s2,8);
      float invs = rsqrtf(s2*(1.f/64.f) + 1e-5f);
#pragma unroll
      for (int nt = 0; nt < 4; ++nt){
        int col = nt*16 + colL;
        hnv[i][nt] = (vals[i][nt]-mu)*invs*cb[192+col] + cb[256+col];
      }
    }
#pragma unroll
    for (int i = 0; i < 4; ++i)
#pragma unroll
      for (int nt = 0; nt < 4; ++nt)
        hw[(quad*4+i)*72 + nt*16 + colL] = f2bf(hnv[i][nt]);

    f32x4 a3[2] = {};
#pragma unroll
    for (int kc = 0; kc < 64; kc += 32){
      s16x8 a = ld8(&hw[colL*72 + kc + quad*8]);
#pragma unroll
      for (int nt = 0; nt < 2; ++nt)
        a3[nt] = mfma16(a, ld8(&ws1t[(nt*16+colL)*64 + kc + quad*8]), a3[nt]);
    }
    float bs2f = cb[384];
#pragma unroll
    for (int i = 0; i < 4; ++i){
      float p = 0.f;
#pragma unroll
      for (int nt = 0; nt < 2; ++nt){
        int col = nt*16 + colL;
        p += fmaxf(a3[nt][i] + cb[320+col], 0.f) * cb[352+col];
      }
      p += __shfl_xor(p,1); p += __shfl_xor(p,2); p += __shfl_xor(p,4); p += __shfl_xor(p,8);
      if (colL == 0){
        float z = p + bs2f;
        out[row0g + quad*4 + i] = 1.f / (1.f + __expf(-z));
      }
    }
  }
}

extern "C" void kernel_launch(void* const* d_in, const int* in_sizes, int n_in,
                              void* d_out, int out_size, void* d_ws, size_t ws_size,
                              hipStream_t stream)
{
  const float* x    = (const float*)d_in[0];
  const int*   rank = (const int*)d_in[1];
  const float* Wp   = (const float*)d_in[2];
  const float* bp   = (const float*)d_in[3];
  const float* Wq   = (const float*)d_in[4];
  const float* bq   = (const float*)d_in[5];
  const float* Wk   = (const float*)d_in[6];
  const float* bk   = (const float*)d_in[7];
  const float* Wv   = (const float*)d_in[8];
  const float* bv   = (const float*)d_in[9];
  const float* Ee   = (const float*)d_in[10];
  const float* Wr1  = (const float*)d_in[11];
  const float* br1  = (const float*)d_in[12];
  const float* Wr2  = (const float*)d_in[13];
  const float* Wf1  = (const float*)d_in[14];
  const float* bf1  = (const float*)d_in[15];
  const float* Wf2  = (const float*)d_in[16];
  const float* bf2  = (const float*)d_in[17];
  const float* lng  = (const float*)d_in[18];
  const float* lnb  = (const float*)d_in[19];
  const float* Ws1  = (const float*)d_in[20];
  const float* bs1  = (const float*)d_in[21];
  const float* Ws2  = (const float*)d_in[22];
  const float* bs2  = (const float*)d_in[23];
  float* out = (float*)d_out;

  char* ws = (char*)d_ws;
  float*          rel_t = (float*)(ws + 0);
  unsigned short* q     = (unsigned short*)(ws + 256);
  unsigned short* kk    = (unsigned short*)(ws + 256 + 1*1048576);
  unsigned short* vt    = (unsigned short*)(ws + 256 + 2*1048576);
  unsigned short* wf1t  = (unsigned short*)(ws + 3203328);
  unsigned short* wf2t  = (unsigned short*)(ws + 3219712);
  unsigned short* ws1t  = (unsigned short*)(ws + 3236096);
  float*          cbp   = (float*)(ws + 3240192);

  k_proj<<<dim3(256), dim3(256), 0, stream>>>(x, Wp, bp, Wq, bq, Wk, bk, Wv, bv,
                                              Ee, Wr1, br1, Wr2,
                                              Wf1, bf1, Wf2, bf2, lng, lnb,
                                              Ws1, bs1, Ws2, bs2,
                                              q, kk, vt,
                                              wf1t, wf2t, ws1t, cbp, rel_t);
  k_attn_ffn<<<dim3(32, 16), dim3(256), 0, stream>>>(q, kk, vt, rank, rel_t,
                                              wf1t, wf2t, ws1t, cbp, out);
}